// Round 1
// 3138.630 us; speedup vs baseline: 1.0443x; 1.0443x over previous
//
#include <hip/hip_runtime.h>
#include <math.h>

#define BATCH   4
#define SEQ     2048
#define DMODEL  1024
#define NH      16
#define DHEAD   64
#define OUT_ELEMS   ((size_t)BATCH * SEQ * DMODEL)      // 8388608
#define HEAD_STRIDE ((size_t)SEQ * DHEAD)               // 131072
#define NTILE       (SEQ / 64)                          // 32 key tiles per row
#define STATS_Z     ((size_t)NTILE * SEQ)               // 65536 stats per z

// ---------------------------------------------------------------------------
// Projection GEMM: Y = X(M,1024) @ W(1024,1024) + b
// 128x128 tile, BK=16, 256 threads, 8x8 micro-tile (split 4+4 rows/cols).
// split_heads=1: Y scattered to (B,H,S,64) layout; else row-major (M,1024).
// ---------------------------------------------------------------------------
__global__ __launch_bounds__(256) void proj_gemm_kernel(
    const float* __restrict__ A, const float* __restrict__ W,
    const float* __restrict__ bias, float* __restrict__ out, int split_heads)
{
    __shared__ __align__(16) float As[16][132];  // [k][m], pad keeps 16B align + 2-way banks
    __shared__ __align__(16) float Bs[16][128];  // [k][n]
    const int tid = threadIdx.x;
    const int tx = tid & 15;
    const int ty = tid >> 4;
    const int m0 = blockIdx.y * 128;
    const int n0 = blockIdx.x * 128;

    float acc[8][8];
#pragma unroll
    for (int i = 0; i < 8; ++i)
#pragma unroll
        for (int j = 0; j < 8; ++j) acc[i][j] = 0.f;

    const int am = tid >> 1;           // 0..127 (A tile row)
    const int ak = (tid & 1) * 8;      // 0 or 8 (A tile col base)
    const int bk = tid >> 4;           // 0..15  (B tile row)
    const int bn = (tid & 15) * 8;     // B tile col base

    for (int k0 = 0; k0 < DMODEL; k0 += 16) {
        float4 a0 = *(const float4*)(A + (size_t)(m0 + am) * DMODEL + k0 + ak);
        float4 a1 = *(const float4*)(A + (size_t)(m0 + am) * DMODEL + k0 + ak + 4);
        float4 b0 = *(const float4*)(W + (size_t)(k0 + bk) * DMODEL + n0 + bn);
        float4 b1 = *(const float4*)(W + (size_t)(k0 + bk) * DMODEL + n0 + bn + 4);
        // transpose A into [k][m]
        As[ak + 0][am] = a0.x; As[ak + 1][am] = a0.y;
        As[ak + 2][am] = a0.z; As[ak + 3][am] = a0.w;
        As[ak + 4][am] = a1.x; As[ak + 5][am] = a1.y;
        As[ak + 6][am] = a1.z; As[ak + 7][am] = a1.w;
        *(float4*)&Bs[bk][bn]     = b0;
        *(float4*)&Bs[bk][bn + 4] = b1;
        __syncthreads();
#pragma unroll
        for (int k = 0; k < 16; ++k) {
            float4 x0 = *(const float4*)&As[k][ty * 4];
            float4 x1 = *(const float4*)&As[k][64 + ty * 4];
            float4 y0 = *(const float4*)&Bs[k][tx * 4];
            float4 y1 = *(const float4*)&Bs[k][64 + tx * 4];
            float a[8] = {x0.x, x0.y, x0.z, x0.w, x1.x, x1.y, x1.z, x1.w};
            float b[8] = {y0.x, y0.y, y0.z, y0.w, y1.x, y1.y, y1.z, y1.w};
#pragma unroll
            for (int i = 0; i < 8; ++i)
#pragma unroll
                for (int j = 0; j < 8; ++j)
                    acc[i][j] = fmaf(a[i], b[j], acc[i][j]);
        }
        __syncthreads();
    }

#pragma unroll
    for (int ih = 0; ih < 2; ++ih) {
#pragma unroll
        for (int i = 0; i < 4; ++i) {
            const int m  = m0 + ih * 64 + ty * 4 + i;
            const int bb = m >> 11;       // batch
            const int s  = m & 2047;      // seq pos
#pragma unroll
            for (int jh = 0; jh < 2; ++jh) {
                const int n = n0 + jh * 64 + tx * 4;
                float4 r;
                r.x = acc[ih * 4 + i][jh * 4 + 0] + bias[n + 0];
                r.y = acc[ih * 4 + i][jh * 4 + 1] + bias[n + 1];
                r.z = acc[ih * 4 + i][jh * 4 + 2] + bias[n + 2];
                r.w = acc[ih * 4 + i][jh * 4 + 3] + bias[n + 3];
                if (split_heads) {
                    const int h = n >> 6, d = n & 63;
                    *(float4*)(out + (((size_t)(bb * NH + h) * SEQ + s) * DHEAD + d)) = r;
                } else {
                    *(float4*)(out + (size_t)m * DMODEL + n) = r;
                }
            }
        }
    }
}

// ---------------------------------------------------------------------------
// Fused: masked scaled logits  L[s,t] = 0.125*QK^T - 1e9*mask, written to the
// attn region, PLUS per-64-tile softmax partials: row max m and row sum of
// exp(x-m), written to Mpart/Lpart scratch (the `out` region of d_out, which
// is dead until the final projection).
// ---------------------------------------------------------------------------
__global__ __launch_bounds__(256) void qk_logits_kernel(
    const float* __restrict__ Qh, const float* __restrict__ Kh,
    const float* __restrict__ mask, float* __restrict__ logits,
    float* __restrict__ Mpart, float* __restrict__ Lpart)
{
    __shared__ __align__(16) float Qs[64][68];  // [d][s]  (transposed)
    __shared__ __align__(16) float Ks[64][68];  // [d][t]  (transposed)
    const int tid = threadIdx.x;
    const int tx = tid & 15, ty = tid >> 4;
    const int t0 = blockIdx.x * 64;
    const int s0 = blockIdx.y * 64;
    const int z  = blockIdx.z;                  // b*16 + h
    const int b  = z >> 4;
    const float* Qb = Qh + (size_t)z * HEAD_STRIDE;
    const float* Kb = Kh + (size_t)z * HEAD_STRIDE;

    const int r = tid >> 2;       // 0..63 tile row
    const int c = tid & 3;        // 0..3
#pragma unroll
    for (int qq = 0; qq < 4; ++qq) {
        const int col = qq * 16 + c * 4;     // contiguous 64B per row per qq
        float4 qv = *(const float4*)(Qb + (size_t)(s0 + r) * DHEAD + col);
        float4 kv = *(const float4*)(Kb + (size_t)(t0 + r) * DHEAD + col);
        Qs[col + 0][r] = qv.x; Qs[col + 1][r] = qv.y;
        Qs[col + 2][r] = qv.z; Qs[col + 3][r] = qv.w;
        Ks[col + 0][r] = kv.x; Ks[col + 1][r] = kv.y;
        Ks[col + 2][r] = kv.z; Ks[col + 3][r] = kv.w;
    }
    __syncthreads();

    float acc[4][4];
#pragma unroll
    for (int i = 0; i < 4; ++i)
#pragma unroll
        for (int j = 0; j < 4; ++j) acc[i][j] = 0.f;

#pragma unroll 16
    for (int d = 0; d < 64; ++d) {
        float4 qv = *(const float4*)&Qs[d][ty * 4];
        float4 kv = *(const float4*)&Ks[d][tx * 4];
        float a[4] = {qv.x, qv.y, qv.z, qv.w};
        float b2[4] = {kv.x, kv.y, kv.z, kv.w};
#pragma unroll
        for (int i = 0; i < 4; ++i)
#pragma unroll
            for (int j = 0; j < 4; ++j)
                acc[i][j] = fmaf(a[i], b2[j], acc[i][j]);
    }

    // apply scale + mask into x[4][4]
    const float* mb = mask + (size_t)b * SEQ * SEQ;
    float x[4][4];
#pragma unroll
    for (int i = 0; i < 4; ++i) {
        const int s = s0 + ty * 4 + i;
        float4 mv = *(const float4*)(mb + (size_t)s * SEQ + t0 + tx * 4);
        x[i][0] = acc[i][0] * 0.125f - 1e9f * mv.x;
        x[i][1] = acc[i][1] * 0.125f - 1e9f * mv.y;
        x[i][2] = acc[i][2] * 0.125f - 1e9f * mv.z;
        x[i][3] = acc[i][3] * 0.125f - 1e9f * mv.w;
    }

    // per-row (64-wide) partial stats: lanes with same ty hold the row;
    // tx groups are 16 consecutive lanes -> shfl_xor 8/4/2/1 stays in-group.
#pragma unroll
    for (int i = 0; i < 4; ++i) {
        float lm = fmaxf(fmaxf(x[i][0], x[i][1]), fmaxf(x[i][2], x[i][3]));
#pragma unroll
        for (int off = 8; off; off >>= 1)
            lm = fmaxf(lm, __shfl_xor(lm, off, 64));
        float es = __expf(x[i][0] - lm) + __expf(x[i][1] - lm)
                 + __expf(x[i][2] - lm) + __expf(x[i][3] - lm);
#pragma unroll
        for (int off = 8; off; off >>= 1)
            es += __shfl_xor(es, off, 64);
        if (tx == 0) {
            const size_t idx = (size_t)z * STATS_Z + (size_t)blockIdx.x * SEQ
                             + s0 + ty * 4 + i;
            Mpart[idx] = lm;
            Lpart[idx] = es;
        }
    }

    // write raw masked logits
    float* Lb = logits + (size_t)z * SEQ * SEQ;
#pragma unroll
    for (int i = 0; i < 4; ++i) {
        float4 rr;
        rr.x = x[i][0]; rr.y = x[i][1]; rr.z = x[i][2]; rr.w = x[i][3];
        *(float4*)(Lb + (size_t)(s0 + ty * 4 + i) * SEQ + t0 + tx * 4) = rr;
    }
}

// ---------------------------------------------------------------------------
// Fold 32 per-tile partials per (z,s) row into final M and 1/S, written
// in-place into the tile-0 slots of Mpart/Lpart. Each thread only overwrites
// its own row's already-consumed slots -> race-free. ~68 MB traffic.
// ---------------------------------------------------------------------------
__global__ __launch_bounds__(256) void stats_reduce_kernel(
    float* __restrict__ Mp, float* __restrict__ Lp)
{
    const int s = blockIdx.x * 256 + threadIdx.x;
    const int z = blockIdx.y;
    const size_t base = (size_t)z * STATS_Z + s;
    float mv[NTILE];
    float M = -INFINITY;
#pragma unroll
    for (int t = 0; t < NTILE; ++t) {
        mv[t] = Mp[base + (size_t)t * SEQ];
        M = fmaxf(M, mv[t]);
    }
    float S = 0.f;
#pragma unroll
    for (int t = 0; t < NTILE; ++t)
        S += Lp[base + (size_t)t * SEQ] * __expf(mv[t] - M);
    Mp[base] = M;
    Lp[base] = 1.0f / S;
}

// ---------------------------------------------------------------------------
// Fused finalize + PV: read raw logits, p = exp(x - M) * invS, write p back
// (this IS the attn output), accumulate ctx += p @ V. ctx in (B,S,H,D).
// ---------------------------------------------------------------------------
__global__ __launch_bounds__(256) void attn_v_kernel(
    float* __restrict__ attn, const float* __restrict__ Vh,
    const float* __restrict__ Mfin, const float* __restrict__ Linv,
    float* __restrict__ ctx)
{
    __shared__ __align__(16) float As_T[64][68];  // [t][s] (transposed p tile)
    __shared__ __align__(16) float Vs[64][68];    // [t][d]
    __shared__ float Ms[64], Ls[64];
    const int tid = threadIdx.x;
    const int tx = tid & 15, ty = tid >> 4;
    const int s0 = blockIdx.x * 64;
    const int z  = blockIdx.y;                    // b*16 + h
    const int b  = z >> 4, h = z & 15;
    float* Ab = attn + (size_t)z * SEQ * SEQ;
    const float* Vb = Vh + (size_t)z * HEAD_STRIDE;
    const int r = tid >> 2, c = tid & 3;

    if (tid < 64) {
        Ms[tid] = Mfin[(size_t)z * STATS_Z + s0 + tid];  // tile-0 slot = final M
        Ls[tid] = Linv[(size_t)z * STATS_Z + s0 + tid];  // tile-0 slot = 1/S
    }
    __syncthreads();
    const float Mr = Ms[r];   // stats for the s-row this thread loads
    const float Lr = Ls[r];

    float acc[4][4];
#pragma unroll
    for (int i = 0; i < 4; ++i)
#pragma unroll
        for (int j = 0; j < 4; ++j) acc[i][j] = 0.f;

    for (int t0 = 0; t0 < SEQ; t0 += 64) {
#pragma unroll
        for (int qq = 0; qq < 4; ++qq) {
            const int col = qq * 16 + c * 4;
            float* ap = Ab + (size_t)(s0 + r) * SEQ + t0 + col;
            float4 av = *(const float4*)ap;
            float4 p;
            p.x = __expf(av.x - Mr) * Lr;
            p.y = __expf(av.y - Mr) * Lr;
            p.z = __expf(av.z - Mr) * Lr;
            p.w = __expf(av.w - Mr) * Lr;
            *(float4*)ap = p;                      // attn output (RMW same line)
            As_T[col + 0][r] = p.x; As_T[col + 1][r] = p.y;
            As_T[col + 2][r] = p.z; As_T[col + 3][r] = p.w;
            float4 vv = *(const float4*)(Vb + (size_t)(t0 + r) * DHEAD + col);
            *(float4*)&Vs[r][col] = vv;
        }
        __syncthreads();
#pragma unroll 16
        for (int t = 0; t < 64; ++t) {
            float4 av = *(const float4*)&As_T[t][ty * 4];
            float4 vv = *(const float4*)&Vs[t][tx * 4];
            float a[4] = {av.x, av.y, av.z, av.w};
            float v[4] = {vv.x, vv.y, vv.z, vv.w};
#pragma unroll
            for (int i = 0; i < 4; ++i)
#pragma unroll
                for (int j = 0; j < 4; ++j)
                    acc[i][j] = fmaf(a[i], v[j], acc[i][j]);
        }
        __syncthreads();
    }

#pragma unroll
    for (int i = 0; i < 4; ++i) {
        float4 rr;
        rr.x = acc[i][0]; rr.y = acc[i][1]; rr.z = acc[i][2]; rr.w = acc[i][3];
        *(float4*)(ctx + ((size_t)b * SEQ + s0 + ty * 4 + i) * DMODEL + h * DHEAD + tx * 4) = rr;
    }
}

// ---------------------------------------------------------------------------
extern "C" void kernel_launch(void* const* d_in, const int* in_sizes, int n_in,
                              void* d_out, int out_size, void* d_ws, size_t ws_size,
                              hipStream_t stream)
{
    const float* q    = (const float*)d_in[0];
    const float* k    = (const float*)d_in[1];
    const float* v    = (const float*)d_in[2];
    const float* mask = (const float*)d_in[3];
    const float* Wq   = (const float*)d_in[4];
    const float* bq   = (const float*)d_in[5];
    const float* Wk   = (const float*)d_in[6];
    const float* bk   = (const float*)d_in[7];
    const float* Wv   = (const float*)d_in[8];
    const float* bv   = (const float*)d_in[9];
    const float* Wo   = (const float*)d_in[10];
    const float* bo   = (const float*)d_in[11];

    float* out  = (float*)d_out;
    float* attn = out + OUT_ELEMS;                      // 268,435,456 floats

    // softmax stats scratch: the `out` region is dead until the final
    // projection. Mpart+Lpart = 2 * 64*32*2048 = 8,388,608 floats = OUT_ELEMS.
    float* Mpart = out;
    float* Lpart = out + (size_t)BATCH * NH * STATS_Z;  // out + 4,194,304

    float* ws  = (float*)d_ws;
    const size_t HBUF = (size_t)BATCH * NH * SEQ * DHEAD;  // 8,388,608 floats
    float* Qh  = ws;
    float* Kh  = ws + HBUF;
    float* Vh  = ws + 2 * HBUF;
    float* ctx = ws;          // reuse Qh region: Qh dead after qk_logits

    dim3 blk(256);
    // Q/K/V projections -> head-split layout in workspace
    proj_gemm_kernel<<<dim3(8, 64), blk, 0, stream>>>(q, Wq, bq, Qh, 1);
    proj_gemm_kernel<<<dim3(8, 64), blk, 0, stream>>>(k, Wk, bk, Kh, 1);
    proj_gemm_kernel<<<dim3(8, 64), blk, 0, stream>>>(v, Wv, bv, Vh, 1);
    // masked scaled logits + per-tile softmax partials
    qk_logits_kernel<<<dim3(32, 32, 64), blk, 0, stream>>>(Qh, Kh, mask, attn,
                                                           Mpart, Lpart);
    // fold partials -> final M, 1/S (in-place, tile-0 slots)
    stats_reduce_kernel<<<dim3(SEQ / 256, BATCH * NH), blk, 0, stream>>>(Mpart, Lpart);
    // finalize p (write attn output) + ctx = p @ V   (ctx overwrites Qh)
    attn_v_kernel<<<dim3(32, 64), blk, 0, stream>>>(attn, Vh, Mpart, Lpart, ctx);
    // out = ctx @ Wo + bo  (overwrites the stats scratch, which is now dead)
    proj_gemm_kernel<<<dim3(8, 64), blk, 0, stream>>>(ctx, Wo, bo, out, 0);
}

// Round 2
// 2450.532 us; speedup vs baseline: 1.3375x; 1.2808x over previous
//
#include <hip/hip_runtime.h>
#include <math.h>

#define BATCH   4
#define SEQ     2048
#define DMODEL  1024
#define NH      16
#define DHEAD   64
#define OUT_ELEMS   ((size_t)BATCH * SEQ * DMODEL)      // 8388608
#define HEAD_STRIDE ((size_t)SEQ * DHEAD)               // 131072
#define NTILE       (SEQ / 64)                          // 32 key tiles per row
#define STATS_Z     ((size_t)NTILE * SEQ)               // 65536 stats per z
#define HBUF        ((size_t)BATCH * NH * SEQ * DHEAD)  // 8388608 elements
#define WPLANE      1048576                             // ushorts per W plane

typedef __attribute__((ext_vector_type(8))) short bf16x8_t;
typedef __attribute__((ext_vector_type(4))) float f32x4_t;

__device__ __forceinline__ unsigned short bf16_rn(float x) {
    unsigned u = __float_as_uint(x);
    return (unsigned short)((u + 0x7FFFu + ((u >> 16) & 1u)) >> 16);
}
__device__ __forceinline__ float bf16_f32(unsigned short h) {
    return __uint_as_float((unsigned)h << 16);
}

// ---------------------------------------------------------------------------
// Split fp32 tensor into bf16 hi/lo planes (same layout). n4 = #float4s.
// ---------------------------------------------------------------------------
__global__ __launch_bounds__(256) void split_f32_kernel(
    const float* __restrict__ in, ushort* __restrict__ hi,
    ushort* __restrict__ lo, int n4)
{
    for (int i = blockIdx.x * 256 + threadIdx.x; i < n4; i += gridDim.x * 256) {
        float4 v = ((const float4*)in)[i];
        ushort4 h, l;
        h.x = bf16_rn(v.x); l.x = bf16_rn(v.x - bf16_f32(h.x));
        h.y = bf16_rn(v.y); l.y = bf16_rn(v.y - bf16_f32(h.y));
        h.z = bf16_rn(v.z); l.z = bf16_rn(v.z - bf16_f32(h.z));
        h.w = bf16_rn(v.w); l.w = bf16_rn(v.w - bf16_f32(h.w));
        ((ushort4*)hi)[i] = h;
        ((ushort4*)lo)[i] = l;
    }
}

// ---------------------------------------------------------------------------
// W (1024x1024 fp32, row-major [k][n]) -> pre-tiled bf16 hi/lo fragment image:
// [nb=8][ks=32][fn=8][kh=4][c=16][kk=8], hi plane then lo plane (+WPLANE).
// GEMM staging of a (nb,ks) tile is then a linear 8KB copy per plane.
// ---------------------------------------------------------------------------
__global__ __launch_bounds__(256) void wtile_kernel(
    const float* __restrict__ W, ushort* __restrict__ Wt)
{
    const int idx = blockIdx.x * 256 + threadIdx.x;     // 0..262143
    const int k = idx >> 8;
    const int n4 = (idx & 255) * 4;
    float4 w = *(const float4*)(W + (size_t)k * 1024 + n4);
    const int ks = k >> 5, kh = (k >> 3) & 3, kk = k & 7;
    float wv[4] = {w.x, w.y, w.z, w.w};
#pragma unroll
    for (int j = 0; j < 4; ++j) {
        const int n = n4 + j;
        const int nb = n >> 7, fn = (n >> 4) & 7, c = n & 15;
        const size_t off = (size_t)(nb * 32 + ks) * 4096
                         + (size_t)((fn * 4 + kh) * 16 + c) * 8 + kk;
        unsigned short h = bf16_rn(wv[j]);
        Wt[off] = h;
        Wt[off + WPLANE] = bf16_rn(wv[j] - bf16_f32(h));
    }
}

// ---------------------------------------------------------------------------
// MFMA projection GEMM: Y = A(8192x1024) @ W(1024x1024) + b, split-bf16
// (3 combos: ah*bh + ah*bl + al*bh). 128x128 tile, BK=32, 4 waves (2x2),
// each wave 64x64 = 4x4 fragments of 16x16x32.
// mode 0: fp32 row-major out. mode 1: bf16 hi/lo head-split planes.
// ---------------------------------------------------------------------------
__global__ __launch_bounds__(256) void proj_mfma_kernel(
    const ushort* __restrict__ Ahi, const ushort* __restrict__ Alo,
    const ushort* __restrict__ Wt, const float* __restrict__ bias,
    float* __restrict__ outF, ushort* __restrict__ Yhi,
    ushort* __restrict__ Ylo, int mode)
{
    __shared__ ushort Af[2][4096];   // [plane][fm4? -> fm8][kh4][c16][kk8]
    __shared__ ushort Bf[2][4096];
    const int tid = threadIdx.x;
    const int lane = tid & 63;
    const int w = tid >> 6;
    const int wy = w >> 1, wx = w & 1;
    const int hi16 = lane >> 4, c16 = lane & 15;
    const int m0 = blockIdx.y * 128;
    const int nb = blockIdx.x;                    // n0 = nb*128

    f32x4_t acc[4][4];
#pragma unroll
    for (int i = 0; i < 4; ++i)
#pragma unroll
        for (int j = 0; j < 4; ++j) acc[i][j] = (f32x4_t){0.f, 0.f, 0.f, 0.f};

    for (int ks = 0; ks < 32; ++ks) {
        // stage A (rows m0..m0+127, k ks*32..+31) into fragment layout
#pragma unroll
        for (int p = 0; p < 2; ++p) {
            const int slot = tid + p * 256;       // 0..511
            const int row = slot >> 2, g = slot & 3;
            const size_t ga = (size_t)(m0 + row) * 1024 + ks * 32 + g * 8;
            const int li = ((row >> 4) * 4 + g) * 128 + (row & 15) * 8;
            *(uint4*)&Af[0][li] = *(const uint4*)(Ahi + ga);
            *(uint4*)&Af[1][li] = *(const uint4*)(Alo + ga);
        }
        // stage B: linear copy from pre-tiled W
        const ushort* src = Wt + (size_t)(nb * 32 + ks) * 4096;
#pragma unroll
        for (int p = 0; p < 2; ++p) {
            const int ch = (tid + p * 256) * 8;
            *(uint4*)&Bf[0][ch] = *(const uint4*)(src + ch);
            *(uint4*)&Bf[1][ch] = *(const uint4*)(src + WPLANE + ch);
        }
        __syncthreads();

        bf16x8_t bH[4], bL[4], aH[4], aL[4];
#pragma unroll
        for (int fn = 0; fn < 4; ++fn) {
            const int idx = ((wx * 4 + fn) * 4 + hi16) * 128 + c16 * 8;
            bH[fn] = *(const bf16x8_t*)&Bf[0][idx];
            bL[fn] = *(const bf16x8_t*)&Bf[1][idx];
        }
#pragma unroll
        for (int fm = 0; fm < 4; ++fm) {
            const int idx = ((wy * 4 + fm) * 4 + hi16) * 128 + c16 * 8;
            aH[fm] = *(const bf16x8_t*)&Af[0][idx];
            aL[fm] = *(const bf16x8_t*)&Af[1][idx];
        }
#pragma unroll
        for (int fm = 0; fm < 4; ++fm)
#pragma unroll
            for (int fn = 0; fn < 4; ++fn) {
                acc[fm][fn] = __builtin_amdgcn_mfma_f32_16x16x32_bf16(aH[fm], bH[fn], acc[fm][fn], 0, 0, 0);
                acc[fm][fn] = __builtin_amdgcn_mfma_f32_16x16x32_bf16(aH[fm], bL[fn], acc[fm][fn], 0, 0, 0);
                acc[fm][fn] = __builtin_amdgcn_mfma_f32_16x16x32_bf16(aL[fm], bH[fn], acc[fm][fn], 0, 0, 0);
            }
        __syncthreads();
    }

    float bv[4];
#pragma unroll
    for (int fn = 0; fn < 4; ++fn)
        bv[fn] = bias[nb * 128 + wx * 64 + fn * 16 + c16];

#pragma unroll
    for (int fm = 0; fm < 4; ++fm) {
        const int mbase = m0 + wy * 64 + fm * 16 + hi16 * 4;
#pragma unroll
        for (int fn = 0; fn < 4; ++fn) {
            const int n = nb * 128 + wx * 64 + fn * 16 + c16;
#pragma unroll
            for (int r = 0; r < 4; ++r) {
                const int m = mbase + r;
                const float val = acc[fm][fn][r] + bv[fn];
                if (mode == 0) {
                    outF[(size_t)m * 1024 + n] = val;
                } else {
                    const int z = ((m >> 11) << 4) + (n >> 6);
                    const int sp = m & 2047, d = n & 63;
                    const size_t off = (size_t)z * HEAD_STRIDE + (size_t)sp * 64 + d;
                    unsigned short h = bf16_rn(val);
                    Yhi[off] = h;
                    Ylo[off] = bf16_rn(val - bf16_f32(h));
                }
            }
        }
    }
}

// ---------------------------------------------------------------------------
// MFMA QK^T: L[s,t] = 0.125*Q·K - 1e9*mask; fp32 logits + per-64-tile softmax
// partials. Tile 128s x 64t, 4 waves stacked on s (wave = 32s x 64t).
// K-dim = d = 64 -> 2 MFMA k-steps. Split-bf16 (3 combos).
// ---------------------------------------------------------------------------
__global__ __launch_bounds__(256) void qk_mfma_kernel(
    const ushort* __restrict__ Qhi, const ushort* __restrict__ Qlo,
    const ushort* __restrict__ Khi, const ushort* __restrict__ Klo,
    const float* __restrict__ mask, float* __restrict__ logits,
    float* __restrict__ Mpart, float* __restrict__ Lpart)
{
    __shared__ ushort Qf[2][8192];   // [fm8][g8][c16][kk8]
    __shared__ ushort Kf[2][4096];   // [fn4][g8][c16][kk8]
    const int tid = threadIdx.x;
    const int lane = tid & 63, w = tid >> 6;
    const int hi16 = lane >> 4, c16 = lane & 15;
    const int t0 = blockIdx.x * 64;
    const int s0 = blockIdx.y * 128;
    const int z = blockIdx.z, b = z >> 4;
    const ushort* Qbh = Qhi + (size_t)z * HEAD_STRIDE;
    const ushort* Qbl = Qlo + (size_t)z * HEAD_STRIDE;
    const ushort* Kbh = Khi + (size_t)z * HEAD_STRIDE;
    const ushort* Kbl = Klo + (size_t)z * HEAD_STRIDE;

#pragma unroll
    for (int p = 0; p < 4; ++p) {
        const int ch = tid + p * 256;             // 0..1023
        const int s = ch >> 3, g = ch & 7;
        const size_t ga = (size_t)(s0 + s) * 64 + g * 8;
        const int li = ((s >> 4) * 8 + g) * 128 + (s & 15) * 8;
        *(uint4*)&Qf[0][li] = *(const uint4*)(Qbh + ga);
        *(uint4*)&Qf[1][li] = *(const uint4*)(Qbl + ga);
    }
#pragma unroll
    for (int p = 0; p < 2; ++p) {
        const int ch = tid + p * 256;             // 0..511
        const int t = ch >> 3, g = ch & 7;
        const size_t ga = (size_t)(t0 + t) * 64 + g * 8;
        const int li = ((t >> 4) * 8 + g) * 128 + (t & 15) * 8;
        *(uint4*)&Kf[0][li] = *(const uint4*)(Kbh + ga);
        *(uint4*)&Kf[1][li] = *(const uint4*)(Kbl + ga);
    }
    __syncthreads();

    f32x4_t acc[2][4];
#pragma unroll
    for (int i = 0; i < 2; ++i)
#pragma unroll
        for (int j = 0; j < 4; ++j) acc[i][j] = (f32x4_t){0.f, 0.f, 0.f, 0.f};

    bf16x8_t bH[4][2], bL[4][2];
#pragma unroll
    for (int fn = 0; fn < 4; ++fn)
#pragma unroll
        for (int kq = 0; kq < 2; ++kq) {
            const int idx = (fn * 8 + kq * 4 + hi16) * 128 + c16 * 8;
            bH[fn][kq] = *(const bf16x8_t*)&Kf[0][idx];
            bL[fn][kq] = *(const bf16x8_t*)&Kf[1][idx];
        }
#pragma unroll
    for (int fm = 0; fm < 2; ++fm) {
        bf16x8_t aH[2], aL[2];
        const int fmg = w * 2 + fm;
#pragma unroll
        for (int kq = 0; kq < 2; ++kq) {
            const int idx = (fmg * 8 + kq * 4 + hi16) * 128 + c16 * 8;
            aH[kq] = *(const bf16x8_t*)&Qf[0][idx];
            aL[kq] = *(const bf16x8_t*)&Qf[1][idx];
        }
#pragma unroll
        for (int fn = 0; fn < 4; ++fn)
#pragma unroll
            for (int kq = 0; kq < 2; ++kq) {
                acc[fm][fn] = __builtin_amdgcn_mfma_f32_16x16x32_bf16(aH[kq], bH[fn][kq], acc[fm][fn], 0, 0, 0);
                acc[fm][fn] = __builtin_amdgcn_mfma_f32_16x16x32_bf16(aH[kq], bL[fn][kq], acc[fm][fn], 0, 0, 0);
                acc[fm][fn] = __builtin_amdgcn_mfma_f32_16x16x32_bf16(aL[kq], bH[fn][kq], acc[fm][fn], 0, 0, 0);
            }
    }

    const float* mb = mask + (size_t)b * SEQ * SEQ;
    float* Lb = logits + (size_t)z * SEQ * SEQ;
    float x[2][4][4];
#pragma unroll
    for (int fm = 0; fm < 2; ++fm)
#pragma unroll
        for (int r = 0; r < 4; ++r) {
            const int sp = s0 + w * 32 + fm * 16 + hi16 * 4 + r;
#pragma unroll
            for (int fn = 0; fn < 4; ++fn) {
                const int t = t0 + fn * 16 + c16;
                x[fm][fn][r] = acc[fm][fn][r] * 0.125f
                             - 1e9f * mb[(size_t)sp * SEQ + t];
            }
        }
    // per-row (64-wide) partial stats; row elements live in the 16-lane c-group
#pragma unroll
    for (int fm = 0; fm < 2; ++fm)
#pragma unroll
        for (int r = 0; r < 4; ++r) {
            float lm = fmaxf(fmaxf(x[fm][0][r], x[fm][1][r]),
                             fmaxf(x[fm][2][r], x[fm][3][r]));
#pragma unroll
            for (int off = 8; off; off >>= 1)
                lm = fmaxf(lm, __shfl_xor(lm, off, 64));
            float es = __expf(x[fm][0][r] - lm) + __expf(x[fm][1][r] - lm)
                     + __expf(x[fm][2][r] - lm) + __expf(x[fm][3][r] - lm);
#pragma unroll
            for (int off = 8; off; off >>= 1)
                es += __shfl_xor(es, off, 64);
            if (c16 == 0) {
                const int sp = s0 + w * 32 + fm * 16 + hi16 * 4 + r;
                const size_t sidx = (size_t)z * STATS_Z
                                  + (size_t)blockIdx.x * SEQ + sp;
                Mpart[sidx] = lm;
                Lpart[sidx] = es;
            }
        }
    // write raw masked logits
#pragma unroll
    for (int fm = 0; fm < 2; ++fm)
#pragma unroll
        for (int r = 0; r < 4; ++r) {
            const int sp = s0 + w * 32 + fm * 16 + hi16 * 4 + r;
#pragma unroll
            for (int fn = 0; fn < 4; ++fn)
                Lb[(size_t)sp * SEQ + t0 + fn * 16 + c16] = x[fm][fn][r];
        }
}

// ---------------------------------------------------------------------------
// Transpose V planes [z][t][64] -> [z][d][2048] (bf16 hi/lo), so PV's k-dim
// (t) is contiguous for fragment staging.
// ---------------------------------------------------------------------------
__global__ __launch_bounds__(256) void vt_kernel(
    const ushort* __restrict__ Vhi, const ushort* __restrict__ Vlo,
    ushort* __restrict__ VThi, ushort* __restrict__ VTlo)
{
    __shared__ ushort lds[64 * 72];
    const int tid = threadIdx.x;
    const int t0 = blockIdx.x * 64;
    const int z = blockIdx.y;
    const ushort* src[2] = {Vhi + (size_t)z * HEAD_STRIDE, Vlo + (size_t)z * HEAD_STRIDE};
    ushort* dst[2] = {VThi + (size_t)z * HEAD_STRIDE, VTlo + (size_t)z * HEAD_STRIDE};
#pragma unroll
    for (int p = 0; p < 2; ++p) {
        __syncthreads();
#pragma unroll
        for (int q = 0; q < 2; ++q) {
            const int ch = tid + q * 256;
            const int t = ch >> 3, g = ch & 7;
            *(uint4*)&lds[t * 72 + g * 8] =
                *(const uint4*)(src[p] + (size_t)(t0 + t) * 64 + g * 8);
        }
        __syncthreads();
#pragma unroll
        for (int q = 0; q < 2; ++q) {
            const int ch = tid + q * 256;
            const int d = ch >> 3, gt = ch & 7;
            unsigned pk[4];
#pragma unroll
            for (int j2 = 0; j2 < 4; ++j2)
                pk[j2] = (unsigned)lds[(gt * 8 + 2 * j2) * 72 + d]
                       | ((unsigned)lds[(gt * 8 + 2 * j2 + 1) * 72 + d] << 16);
            uint4 o; o.x = pk[0]; o.y = pk[1]; o.z = pk[2]; o.w = pk[3];
            *(uint4*)&dst[p][(size_t)d * 2048 + t0 + gt * 8] = o;
        }
    }
}

// ---------------------------------------------------------------------------
// Fold 32 per-tile partials per (z,s) row into final M and 1/S (in-place,
// tile-0 slots).
// ---------------------------------------------------------------------------
__global__ __launch_bounds__(256) void stats_reduce_kernel(
    float* __restrict__ Mp, float* __restrict__ Lp)
{
    const int s = blockIdx.x * 256 + threadIdx.x;
    const int z = blockIdx.y;
    const size_t base = (size_t)z * STATS_Z + s;
    float mv[NTILE];
    float M = -INFINITY;
#pragma unroll
    for (int t = 0; t < NTILE; ++t) {
        mv[t] = Mp[base + (size_t)t * SEQ];
        M = fmaxf(M, mv[t]);
    }
    float S = 0.f;
#pragma unroll
    for (int t = 0; t < NTILE; ++t)
        S += Lp[base + (size_t)t * SEQ] * __expf(mv[t] - M);
    Mp[base] = M;
    Lp[base] = 1.0f / S;
}

// ---------------------------------------------------------------------------
// Fused finalize + PV (MFMA): read raw logits, p = exp(x-M)*invS, write p
// back (attn output), P(bf16) @ V(hi/lo bf16) -> ctx written as bf16 hi/lo
// planes in (B,S,H*D) row-major. Tile 128s x 64d, waves 2x2 (64s x 32d each).
// ---------------------------------------------------------------------------
__global__ __launch_bounds__(256) void attn_v_mfma_kernel(
    float* __restrict__ attn, const ushort* __restrict__ VThi,
    const ushort* __restrict__ VTlo, const float* __restrict__ Mfin,
    const float* __restrict__ Linv, ushort* __restrict__ ctx_hi,
    ushort* __restrict__ ctx_lo)
{
    __shared__ ushort Pf[8192];      // [fm8][g8][c16][kk8] single plane
    __shared__ ushort Vf[2][4096];   // [fn4][g8][c16][kk8]
    __shared__ float Ms[128], Ls[128];
    const int tid = threadIdx.x;
    const int lane = tid & 63, w = tid >> 6;
    const int wy = w >> 1, wx = w & 1;
    const int hi16 = lane >> 4, c16 = lane & 15;
    const int s0 = blockIdx.x * 128;
    const int z = blockIdx.y, b = z >> 4, h = z & 15;
    float* Ab = attn + (size_t)z * SEQ * SEQ;
    const ushort* Vbh = VThi + (size_t)z * HEAD_STRIDE;
    const ushort* Vbl = VTlo + (size_t)z * HEAD_STRIDE;

    if (tid < 128) {
        Ms[tid] = Mfin[(size_t)z * STATS_Z + s0 + tid];
        Ls[tid] = Linv[(size_t)z * STATS_Z + s0 + tid];
    }
    __syncthreads();

    f32x4_t acc[4][2];
#pragma unroll
    for (int i = 0; i < 4; ++i)
#pragma unroll
        for (int j = 0; j < 2; ++j) acc[i][j] = (f32x4_t){0.f, 0.f, 0.f, 0.f};

    const int prow = tid >> 4;            // 0..15
    const int pc4 = (tid & 15) * 4;       // 0..60

    for (int t0 = 0; t0 < SEQ; t0 += 64) {
        // stage P: coalesced float4 read of logits, finalize, RMW p, frag write
#pragma unroll
        for (int it = 0; it < 8; ++it) {
            const int r = it * 16 + prow;
            float* ap = Ab + (size_t)(s0 + r) * SEQ + t0 + pc4;
            float4 xv = *(const float4*)ap;
            const float mr = Ms[r], lr = Ls[r];
            float4 pv;
            pv.x = __expf(xv.x - mr) * lr;
            pv.y = __expf(xv.y - mr) * lr;
            pv.z = __expf(xv.z - mr) * lr;
            pv.w = __expf(xv.w - mr) * lr;
            *(float4*)ap = pv;                        // attn output
            uint2 pk;
            pk.x = (unsigned)bf16_rn(pv.x) | ((unsigned)bf16_rn(pv.y) << 16);
            pk.y = (unsigned)bf16_rn(pv.z) | ((unsigned)bf16_rn(pv.w) << 16);
            const int li = ((r >> 4) * 8 + (pc4 >> 3)) * 128 + (r & 15) * 8 + (pc4 & 7);
            *(uint2*)&Pf[li] = pk;
        }
        // stage V^T tile (64d x 64t)
#pragma unroll
        for (int q = 0; q < 2; ++q) {
            const int ch = tid + q * 256;
            const int d = ch >> 3, g = ch & 7;
            const size_t ga = (size_t)d * 2048 + t0 + g * 8;
            const int li = ((d >> 4) * 8 + g) * 128 + (d & 15) * 8;
            *(uint4*)&Vf[0][li] = *(const uint4*)(Vbh + ga);
            *(uint4*)&Vf[1][li] = *(const uint4*)(Vbl + ga);
        }
        __syncthreads();

        bf16x8_t vH[2][2], vL[2][2];
#pragma unroll
        for (int fn = 0; fn < 2; ++fn)
#pragma unroll
            for (int kq = 0; kq < 2; ++kq) {
                const int fng = wx * 2 + fn;
                const int idx = (fng * 8 + kq * 4 + hi16) * 128 + c16 * 8;
                vH[fn][kq] = *(const bf16x8_t*)&Vf[0][idx];
                vL[fn][kq] = *(const bf16x8_t*)&Vf[1][idx];
            }
#pragma unroll
        for (int fm = 0; fm < 4; ++fm) {
            bf16x8_t pA[2];
            const int fmg = wy * 4 + fm;
#pragma unroll
            for (int kq = 0; kq < 2; ++kq)
                pA[kq] = *(const bf16x8_t*)&Pf[(fmg * 8 + kq * 4 + hi16) * 128 + c16 * 8];
#pragma unroll
            for (int fn = 0; fn < 2; ++fn)
#pragma unroll
                for (int kq = 0; kq < 2; ++kq) {
                    acc[fm][fn] = __builtin_amdgcn_mfma_f32_16x16x32_bf16(pA[kq], vH[fn][kq], acc[fm][fn], 0, 0, 0);
                    acc[fm][fn] = __builtin_amdgcn_mfma_f32_16x16x32_bf16(pA[kq], vL[fn][kq], acc[fm][fn], 0, 0, 0);
                }
        }
        __syncthreads();
    }

#pragma unroll
    for (int fm = 0; fm < 4; ++fm)
#pragma unroll
        for (int fn = 0; fn < 2; ++fn) {
            const int d = wx * 32 + fn * 16 + c16;
#pragma unroll
            for (int r = 0; r < 4; ++r) {
                const int sp = s0 + wy * 64 + fm * 16 + hi16 * 4 + r;
                const size_t off = ((size_t)b * SEQ + sp) * DMODEL + h * 64 + d;
                const float val = acc[fm][fn][r];
                unsigned short hh = bf16_rn(val);
                ctx_hi[off] = hh;
                ctx_lo[off] = bf16_rn(val - bf16_f32(hh));
            }
        }
}

// ---------------------------------------------------------------------------
extern "C" void kernel_launch(void* const* d_in, const int* in_sizes, int n_in,
                              void* d_out, int out_size, void* d_ws, size_t ws_size,
                              hipStream_t stream)
{
    const float* q    = (const float*)d_in[0];
    const float* k    = (const float*)d_in[1];
    const float* v    = (const float*)d_in[2];
    const float* mask = (const float*)d_in[3];
    const float* Wq   = (const float*)d_in[4];
    const float* bq   = (const float*)d_in[5];
    const float* Wk   = (const float*)d_in[6];
    const float* bk   = (const float*)d_in[7];
    const float* Wv   = (const float*)d_in[8];
    const float* bv   = (const float*)d_in[9];
    const float* Wo   = (const float*)d_in[10];
    const float* bo   = (const float*)d_in[11];

    float* out  = (float*)d_out;
    float* attn = out + OUT_ELEMS;

    // stats scratch in the (dead-until-final-proj) out region
    float* Mpart = out;
    float* Lpart = out + (size_t)BATCH * NH * STATS_Z;   // out + 4,194,304

    // pre-qk scratch in the (dead-until-qk) attn region:
    //   q/k/v bf16 splits (6 x HBUF ushorts) + Wq/Wk/Wv tiles (6 x WPLANE)
    ushort* qs_hi = (ushort*)attn;
    ushort* qs_lo = qs_hi + HBUF;
    ushort* ks_hi = qs_lo + HBUF;
    ushort* ks_lo = ks_hi + HBUF;
    ushort* vs_hi = ks_lo + HBUF;
    ushort* vs_lo = vs_hi + HBUF;
    ushort* WqT   = vs_lo + HBUF;
    ushort* WkT   = WqT + 2 * (size_t)WPLANE;
    ushort* WvT   = WkT + 2 * (size_t)WPLANE;

    // ws: 6 x HBUF ushorts = 100.7 MB (same footprint as before)
    ushort* ws16  = (ushort*)d_ws;
    ushort* Qh_hi = ws16;
    ushort* Qh_lo = Qh_hi + HBUF;
    ushort* Kh_hi = Qh_lo + HBUF;
    ushort* Kh_lo = Kh_hi + HBUF;
    ushort* Vh_hi = Kh_lo + HBUF;
    ushort* Vh_lo = Vh_hi + HBUF;
    // region reuse (stream-ordered): VT over Qh (dead after qk),
    // ctx over Kh (dead after qk), WoT over Vh (dead after vt)
    ushort* VT_hi  = Qh_hi;
    ushort* VT_lo  = Qh_lo;
    ushort* ctx_hi = Kh_hi;
    ushort* ctx_lo = Kh_lo;
    ushort* WoT    = Vh_hi;

    dim3 blk(256);
    const int n4 = (int)(OUT_ELEMS / 4);   // float4s per input tensor

    // split inputs into bf16 hi/lo planes (scratch in attn region)
    split_f32_kernel<<<dim3(2048), blk, 0, stream>>>(q, qs_hi, qs_lo, n4);
    split_f32_kernel<<<dim3(2048), blk, 0, stream>>>(k, ks_hi, ks_lo, n4);
    split_f32_kernel<<<dim3(2048), blk, 0, stream>>>(v, vs_hi, vs_lo, n4);
    // pre-tile W splits
    wtile_kernel<<<dim3(1024), blk, 0, stream>>>(Wq, WqT);
    wtile_kernel<<<dim3(1024), blk, 0, stream>>>(Wk, WkT);
    wtile_kernel<<<dim3(1024), blk, 0, stream>>>(Wv, WvT);
    // projections -> head-split bf16 hi/lo planes
    proj_mfma_kernel<<<dim3(8, 64), blk, 0, stream>>>(qs_hi, qs_lo, WqT, bq, nullptr, Qh_hi, Qh_lo, 1);
    proj_mfma_kernel<<<dim3(8, 64), blk, 0, stream>>>(ks_hi, ks_lo, WkT, bk, nullptr, Kh_hi, Kh_lo, 1);
    proj_mfma_kernel<<<dim3(8, 64), blk, 0, stream>>>(vs_hi, vs_lo, WvT, bv, nullptr, Vh_hi, Vh_lo, 1);
    // masked scaled logits + per-tile softmax partials
    qk_mfma_kernel<<<dim3(32, 16, 64), blk, 0, stream>>>(Qh_hi, Qh_lo, Kh_hi, Kh_lo,
                                                         mask, attn, Mpart, Lpart);
    // V -> V^T planes (into dead Qh region)
    vt_kernel<<<dim3(32, 64), blk, 0, stream>>>(Vh_hi, Vh_lo, VT_hi, VT_lo);
    // Wo tile (into dead Vh region)
    wtile_kernel<<<dim3(1024), blk, 0, stream>>>(Wo, WoT);
    // fold partials -> final M, 1/S
    stats_reduce_kernel<<<dim3(SEQ / 256, BATCH * NH), blk, 0, stream>>>(Mpart, Lpart);
    // finalize p (attn output) + ctx = P @ V (ctx hi/lo into dead Kh region)
    attn_v_mfma_kernel<<<dim3(16, 64), blk, 0, stream>>>(attn, VT_hi, VT_lo,
                                                         Mpart, Lpart, ctx_hi, ctx_lo);
    // out = ctx @ Wo + bo
    proj_mfma_kernel<<<dim3(8, 64), blk, 0, stream>>>(ctx_hi, ctx_lo, WoT, bo, out, nullptr, nullptr, 0);
}